// Round 10
// baseline (520.993 us; speedup 1.0000x reference)
//
#include <hip/hip_runtime.h>
#include <hip/hip_cooperative_groups.h>
namespace cg = cooperative_groups;

#define NDRUG 591
#define FDIM 1024
#define NEDGE 120000
#define MPAD 640
#define ASTRIDE 349281          // 591*591 fp32 temp adjacency
#define ABSTRIDE (MPAD*MPAD)
#define HSTRIDE (MPAD*FDIM)
#define REAL (NDRUG*FDIM)
#define WSTRIDE (FDIM*FDIM)
#define NBLK 256
#define NTHR 256
#define GSTR (NBLK*NTHR)
#define NTILE 480               // 3 graphs x 16 n-tiles x 10 m-tiles

typedef __attribute__((ext_vector_type(8))) short bf16x8;
typedef __attribute__((ext_vector_type(4))) float f32x4;
typedef __attribute__((ext_vector_type(4))) unsigned short u16x4;

static __device__ __forceinline__ unsigned short f2bf(float f) {
    unsigned u = __builtin_bit_cast(unsigned, f);
    u += 0x7fffu + ((u >> 16) & 1u);            // RNE
    return (unsigned short)(u >> 16);
}
static __device__ __forceinline__ float bf2f(unsigned short h) {
    return __builtin_bit_cast(float, ((unsigned)h) << 16);
}

typedef const __attribute__((address_space(1))) unsigned int* gp1_t;
typedef __attribute__((address_space(3))) unsigned int* lp3_t;
static __device__ __forceinline__ void gload16(const void* g, unsigned short* l) {
    __builtin_amdgcn_global_load_lds((gp1_t)g, (lp3_t)l, 16, 0, 0);
}

// ---------------- shared GEMM tile routine (device) ----------------
// 64x64 tile, counted-vmcnt 2-phase. EPI=0: C^T bf16 store; EPI=1: +bias relu + pool.
template <int EPI>
static __device__ __forceinline__ void gemm_tile(
    const unsigned short* __restrict__ A, int ldaK,
    const unsigned short* __restrict__ B, int ldbK,
    const float* __restrict__ bias,
    unsigned short* __restrict__ C, int ldC, int K,
    float* __restrict__ poolslot, int m0, int n0,
    unsigned short (&ldsA)[2][4096], unsigned short (&ldsB)[2][4096], float* aux)
{
    const int tid = threadIdx.x;
    const int w = tid >> 6, lane = tid & 63;
    const int l15 = lane & 15, lq = lane >> 4;
    const int wm = w >> 1, wn = w & 1;

    const int sr  = lane >> 3;
    const int kcs = 8 * ((lane & 7) ^ sr);
    const int segA0 = 2 * w, segA1 = 2 * w + 1;
    const int rA0 = segA0 * 8 + sr, rA1 = segA1 * 8 + sr;

    int offA[2][2], offB[2][2];
    {
        int ra0 = 32 * wm + l15, ra1 = ra0 + 16;
        int rb0 = 32 * wn + l15, rb1 = rb0 + 16;
        offA[0][0] = ra0 * 64 + ((lq    ) ^ (ra0 & 7)) * 8;
        offA[0][1] = ra0 * 64 + ((lq + 4) ^ (ra0 & 7)) * 8;
        offA[1][0] = ra1 * 64 + ((lq    ) ^ (ra1 & 7)) * 8;
        offA[1][1] = ra1 * 64 + ((lq + 4) ^ (ra1 & 7)) * 8;
        offB[0][0] = rb0 * 64 + ((lq    ) ^ (rb0 & 7)) * 8;
        offB[0][1] = rb0 * 64 + ((lq + 4) ^ (rb0 & 7)) * 8;
        offB[1][0] = rb1 * 64 + ((lq    ) ^ (rb1 & 7)) * 8;
        offB[1][1] = rb1 * 64 + ((lq + 4) ^ (rb1 & 7)) * 8;
    }

    f32x4 acc00 = {0.f,0.f,0.f,0.f}, acc01 = {0.f,0.f,0.f,0.f};
    f32x4 acc10 = {0.f,0.f,0.f,0.f}, acc11 = {0.f,0.f,0.f,0.f};
    const int nt = K >> 6;

#define STAGE(bf, k0c) do {                                                        \
    gload16(A + (long)(m0 + rA0) * ldaK + (k0c) + kcs, &ldsA[bf][segA0 * 512]);    \
    gload16(A + (long)(m0 + rA1) * ldaK + (k0c) + kcs, &ldsA[bf][segA1 * 512]);    \
    gload16(B + (long)(n0 + rA0) * ldbK + (k0c) + kcs, &ldsB[bf][segA0 * 512]);    \
    gload16(B + (long)(n0 + rA1) * ldbK + (k0c) + kcs, &ldsB[bf][segA1 * 512]);    \
} while (0)

    STAGE(0, 0);
    for (int t = 0; t < nt; ++t) {
        const int cur = t & 1;
        if (t + 1 < nt) {
            STAGE(cur ^ 1, (t + 1) << 6);
            asm volatile("s_waitcnt vmcnt(4)");
        } else {
            asm volatile("s_waitcnt vmcnt(0)");
        }
        __builtin_amdgcn_s_barrier();
        __builtin_amdgcn_sched_barrier(0);
        const unsigned short* pa = ldsA[cur];
        const unsigned short* pb = ldsB[cur];
        {
            bf16x8 a0 = *(const bf16x8*)(pa + offA[0][0]);
            bf16x8 a1 = *(const bf16x8*)(pa + offA[1][0]);
            bf16x8 b0 = *(const bf16x8*)(pb + offB[0][0]);
            bf16x8 b1 = *(const bf16x8*)(pb + offB[1][0]);
            acc00 = __builtin_amdgcn_mfma_f32_16x16x32_bf16(a0, b0, acc00, 0, 0, 0);
            acc01 = __builtin_amdgcn_mfma_f32_16x16x32_bf16(a0, b1, acc01, 0, 0, 0);
            acc10 = __builtin_amdgcn_mfma_f32_16x16x32_bf16(a1, b0, acc10, 0, 0, 0);
            acc11 = __builtin_amdgcn_mfma_f32_16x16x32_bf16(a1, b1, acc11, 0, 0, 0);
        }
        {
            bf16x8 a0 = *(const bf16x8*)(pa + offA[0][1]);
            bf16x8 a1 = *(const bf16x8*)(pa + offA[1][1]);
            bf16x8 b0 = *(const bf16x8*)(pb + offB[0][1]);
            bf16x8 b1 = *(const bf16x8*)(pb + offB[1][1]);
            acc00 = __builtin_amdgcn_mfma_f32_16x16x32_bf16(a0, b0, acc00, 0, 0, 0);
            acc01 = __builtin_amdgcn_mfma_f32_16x16x32_bf16(a0, b1, acc01, 0, 0, 0);
            acc10 = __builtin_amdgcn_mfma_f32_16x16x32_bf16(a1, b0, acc10, 0, 0, 0);
            acc11 = __builtin_amdgcn_mfma_f32_16x16x32_bf16(a1, b1, acc11, 0, 0, 0);
        }
        asm volatile("s_waitcnt lgkmcnt(0)");
        __builtin_amdgcn_sched_barrier(0);
        __builtin_amdgcn_s_barrier();
    }
#undef STAGE

    if (EPI == 0) {
#define TSTORE(accv, mo, no) do {                                   \
        int nn = n0 + 32 * wn + (no) * 16 + l15;                    \
        int mm = m0 + 32 * wm + (mo) * 16 + lq * 4;                 \
        u16x4 pk;                                                   \
        pk[0] = f2bf(accv[0]); pk[1] = f2bf(accv[1]);               \
        pk[2] = f2bf(accv[2]); pk[3] = f2bf(accv[3]);               \
        *(u16x4*)&C[(long)nn * ldC + mm] = pk;                      \
} while (0)
        TSTORE(acc00, 0, 0); TSTORE(acc01, 0, 1);
        TSTORE(acc10, 1, 0); TSTORE(acc11, 1, 1);
#undef TSTORE
    } else {
        float spool = 0.f;
#define NSTORE(accv, mo, no) do {                                   \
        int nn = n0 + 32 * wn + (no) * 16 + l15;                    \
        int mm = m0 + 32 * wm + (mo) * 16 + lq * 4;                 \
        float bs = bias[nn];                                        \
        _Pragma("unroll")                                           \
        for (int i = 0; i < 4; i++) {                               \
            float v = fmaxf(accv[i] + bs, 0.f);                     \
            C[(long)(mm + i) * ldC + nn] = f2bf(v);                 \
            if (mm + i < NDRUG) spool += v;                         \
        }                                                           \
} while (0)
        NSTORE(acc00, 0, 0); NSTORE(acc01, 0, 1);
        NSTORE(acc10, 1, 0); NSTORE(acc11, 1, 1);
#undef NSTORE
#pragma unroll
        for (int off = 32; off > 0; off >>= 1) spool += __shfl_down(spool, off);
        if (lane == 0) aux[w] = spool;
        __syncthreads();
        if (tid == 0) atomicAdd(poolslot, aux[0] + aux[1] + aux[2] + aux[3]);
        __syncthreads();
    }
}

struct MegaParams {
    const float* dm1;
    const int* et; const float* wt;
    const int* es; const float* ws;
    const int* eg; const float* wg;
    const float* W[6];                  // t1,s1,g1,t2,s2,g2
    const float* b1[3]; const float* b2[3];
    const float* fc1w; const float* fc1b;
    const float* fc2w; const float* fc2b;
    const float* convw; const float* convb;
    float* out;
    float* AmatF; float* dinv; float* scal;
    unsigned short* WTb; unsigned short* dm1b; unsigned short* Amatb;
    unsigned short* xwT; unsigned short* h1b; unsigned short* h2b;
};

// ================= cooperative mega kernel (256 blocks, tile-strided) =================
__global__ __launch_bounds__(256, 2) void mega(MegaParams p) {
    __shared__ unsigned short ldsA[2][4096];
    __shared__ unsigned short ldsB[2][4096];
    __shared__ float aux[64];
    cg::grid_group grid = cg::this_grid();
    const int b = blockIdx.x, tid = threadIdx.x;

    // ---- P0: zero fp32 adjacency + pool accumulators ----
    {
        const int TOT = 3 * ASTRIDE;
        for (int i = b * NTHR + tid; i * 4 < TOT; i += GSTR) {
            int e = i * 4;
            if (e + 3 < TOT) *(float4*)(p.AmatF + e) = make_float4(0.f, 0.f, 0.f, 0.f);
            else { for (int j = e; j < TOT; ++j) p.AmatF[j] = 0.f; }
        }
        if (b == 0 && tid < 16) p.scal[tid] = 0.f;
    }
    grid.sync();

    // ---- P1: raw edge scatter + self-loop ----
    {
        const int PER = NEDGE + NDRUG;
        for (int i = b * NTHR + tid; i < 3 * PER; i += GSTR) {
            int g = i / PER, r = i - g * PER;
            float* Ag = p.AmatF + (long)g * ASTRIDE;
            if (r < NEDGE) {
                const int*   E_ = (g == 0) ? p.et : (g == 1) ? p.es : p.eg;
                const float* W_ = (g == 0) ? p.wt : (g == 1) ? p.ws : p.wg;
                atomicAdd(Ag + (long)E_[NEDGE + r] * NDRUG + E_[r], W_[r]);
            } else {
                int n = r - NEDGE;
                atomicAdd(Ag + (long)n * NDRUG + n, 1.0f);
            }
        }
    }
    grid.sync();

    // ---- P2: deg = rowsum(A); dinv = rsqrt ----
    {
        int wv = tid >> 6, lane = tid & 63;
        for (int row = b * 4 + wv; row < 3 * NDRUG; row += NBLK * 4) {
            int g = row / NDRUG, r = row - g * NDRUG;
            const float* src = p.AmatF + (long)g * ASTRIDE + (long)r * NDRUG;
            float s = 0.f;
            for (int c = lane; c < NDRUG; c += 64) s += src[c];
#pragma unroll
            for (int off = 32; off > 0; off >>= 1) s += __shfl_down(s, off);
            if (lane == 0) p.dinv[row] = (s > 0.f) ? rsqrtf(s) : 0.f;
        }
    }
    grid.sync();

    // ---- P3: conversions ----
    {
        for (int r = b; r < MPAD; r += NBLK) {
            int c = tid * 4;
            u16x4 o = {0, 0, 0, 0};
            if (r < NDRUG) {
                float4 v = *(const float4*)(p.dm1 + (long)r * FDIM + c);
                o[0] = f2bf(v.x); o[1] = f2bf(v.y); o[2] = f2bf(v.z); o[3] = f2bf(v.w);
            }
            *(u16x4*)(p.dm1b + (long)r * FDIM + c) = o;
        }
        for (int it = b; it < 3 * MPAD; it += NBLK) {
            int g = it / MPAD, r = it - g * MPAD;
            if (tid < 160) {
                int c = tid * 4;
                u16x4 o = {0, 0, 0, 0};
                if (r < NDRUG) {
                    const float* src = p.AmatF + (long)g * ASTRIDE + (long)r * NDRUG;
                    const float* dv = p.dinv + g * NDRUG;
                    float dr = dv[r];
#pragma unroll
                    for (int j = 0; j < 4; j++) {
                        int cc = c + j;
                        if (cc < NDRUG) o[j] = f2bf(src[cc] * dv[cc] * dr);
                    }
                }
                *(u16x4*)(p.Amatb + (long)g * ABSTRIDE + (long)r * MPAD + c) = o;
            }
        }
        float* ts = (float*)ldsA;
        int tx = tid & 31, ty = tid >> 5;
        for (int tix = b; tix < 6 * 1024; tix += NBLK) {
            int z = tix >> 10, rem = tix & 1023;
            int n0w = (rem & 31) * 32, k0w = (rem >> 5) * 32;
            const float* Wsrc = p.W[z];
            unsigned short* WT = p.WTb + (long)z * WSTRIDE;
            __syncthreads();
#pragma unroll
            for (int q = 0; q < 4; q++)
                ts[(ty + 8 * q) * 33 + tx] = Wsrc[(long)(k0w + ty + 8 * q) * FDIM + n0w + tx];
            __syncthreads();
#pragma unroll
            for (int q = 0; q < 4; q++)
                WT[(long)(n0w + ty + 8 * q) * FDIM + k0w + tx] = f2bf(ts[tx * 33 + ty + 8 * q]);
        }
        __syncthreads();
    }
    grid.sync();

    // ---- P4..P7: GEMM phases, 480 tiles strided over 256 blocks ----
#define TILE_LOOP(body) for (int tl = b; tl < NTILE; tl += NBLK) { \
        int g = tl / 160, rr = tl - g * 160;                        \
        int n0 = (rr & 15) * 64, m0 = (rr >> 4) * 64;               \
        body;                                                       \
    }

    TILE_LOOP(gemm_tile<0>(p.dm1b, FDIM, p.WTb + (long)g * WSTRIDE, FDIM, nullptr,
                           p.xwT + (long)g * HSTRIDE, MPAD, FDIM, nullptr, m0, n0, ldsA, ldsB, aux))
    grid.sync();
    TILE_LOOP(gemm_tile<1>(p.Amatb + (long)g * ABSTRIDE, MPAD, p.xwT + (long)g * HSTRIDE, MPAD,
                           p.b1[g], p.h1b + (long)g * HSTRIDE, FDIM, MPAD,
                           p.scal + 2 * g, m0, n0, ldsA, ldsB, aux))
    grid.sync();
    TILE_LOOP(gemm_tile<0>(p.h1b + (long)g * HSTRIDE, FDIM, p.WTb + (long)(3 + g) * WSTRIDE, FDIM,
                           nullptr, p.xwT + (long)g * HSTRIDE, MPAD, FDIM, nullptr, m0, n0, ldsA, ldsB, aux))
    grid.sync();
    TILE_LOOP(gemm_tile<1>(p.Amatb + (long)g * ABSTRIDE, MPAD, p.xwT + (long)g * HSTRIDE, MPAD,
                           p.b2[g], p.h2b + (long)g * HSTRIDE, FDIM, MPAD,
                           p.scal + 2 * g + 1, m0, n0, ldsA, ldsB, aux))
#undef TILE_LOOP
    grid.sync();

    // ---- P8: SE MLP (block 0) ----
    if (b == 0) {
        int t = tid;
        const float inv = 1.0f / (float)REAL;
        if (t < 6) aux[32 + t] = p.scal[t] * inv;
        __syncthreads();
        if (t < 30) {
            float s = p.fc1b[t];
#pragma unroll
            for (int c = 0; c < 6; c++) s += aux[32 + c] * p.fc1w[t * 6 + c];
            aux[t] = fmaxf(s, 0.f);
        }
        __syncthreads();
        if (t < 64) {
            float hv = (t < 30) ? aux[t] : 0.f;
            for (int j = 0; j < 6; j++) {
                float pr = (t < 30) ? hv * p.fc2w[j * 30 + t] : 0.f;
#pragma unroll
                for (int off = 32; off > 0; off >>= 1) pr += __shfl_down(pr, off);
                if (t == 0)
                    p.scal[8 + j] = p.convw[j] / (1.f + expf(-(p.fc2b[j] + pr)));
            }
        }
    }
    grid.sync();

    // ---- P9: weighted combine ----
    {
        const int nv = REAL / 8;
        float cb = p.convb[0];
        float w0 = p.scal[8], w1 = p.scal[9], w2 = p.scal[10];
        float w3 = p.scal[11], w4 = p.scal[12], w5 = p.scal[13];
        for (int i = b * NTHR + tid; i < nv; i += GSTR) {
            float r8[8];
#pragma unroll
            for (int j = 0; j < 8; j++) r8[j] = cb;
#define ACCCH(wc, ptr) do {                                                 \
            bf16x8 v = *(const bf16x8*)((ptr) + (long)i * 8);               \
            _Pragma("unroll")                                               \
            for (int j = 0; j < 8; j++) r8[j] += (wc) * bf2f((unsigned short)v[j]); \
} while (0)
            ACCCH(w0, p.h1b);
            ACCCH(w1, p.h2b);
            ACCCH(w2, p.h1b + HSTRIDE);
            ACCCH(w3, p.h2b + HSTRIDE);
            ACCCH(w4, p.h1b + 2 * HSTRIDE);
            ACCCH(w5, p.h2b + 2 * HSTRIDE);
#undef ACCCH
            *(float4*)(p.out + (long)i * 8)     = make_float4(r8[0], r8[1], r8[2], r8[3]);
            *(float4*)(p.out + (long)i * 8 + 4) = make_float4(r8[4], r8[5], r8[6], r8[7]);
        }
    }
}

// ================= fallback split kernels (R8-proven path) =================
__global__ void init_kernel(float* AmatF, float* scal) {
    int i = blockIdx.x * blockDim.x + threadIdx.x;
    const int TOT = 3 * ASTRIDE;
    int b = i * 4;
    if (b + 3 < TOT) *(float4*)(AmatF + b) = make_float4(0.f, 0.f, 0.f, 0.f);
    else if (b < TOT) { for (int j = b; j < TOT; ++j) AmatF[j] = 0.f; }
    if (i < 16) scal[i] = 0.f;
}

__global__ void scatter_kernel(const int* e_t, const float* w_t,
                               const int* e_s, const float* w_s,
                               const int* e_g, const float* w_g, float* AmatF) {
    int i = blockIdx.x * blockDim.x + threadIdx.x;
    const int PER = NEDGE + NDRUG;
    if (i >= 3 * PER) return;
    int g = i / PER, r = i - g * PER;
    float* Ag = AmatF + (long)g * ASTRIDE;
    if (r < NEDGE) {
        const int*   E_ = (g == 0) ? e_t : (g == 1) ? e_s : e_g;
        const float* W_ = (g == 0) ? w_t : (g == 1) ? w_s : w_g;
        atomicAdd(Ag + (long)E_[NEDGE + r] * NDRUG + E_[r], W_[r]);
    } else {
        int n = r - NEDGE;
        atomicAdd(Ag + (long)n * NDRUG + n, 1.0f);
    }
}

__global__ void rowdeg_kernel(const float* AmatF, float* dinv) {
    int r = blockIdx.x, g = blockIdx.y;
    const float* row = AmatF + (long)g * ASTRIDE + (long)r * NDRUG;
    float s = 0.f;
    for (int c = threadIdx.x; c < NDRUG; c += 64) s += row[c];
#pragma unroll
    for (int off = 32; off > 0; off >>= 1) s += __shfl_down(s, off);
    if (threadIdx.x == 0) dinv[g * NDRUG + r] = (s > 0.f) ? rsqrtf(s) : 0.f;
}

__global__ void conv_A(const float* AmatF, const float* dinv, unsigned short* Amatb) {
    int r = blockIdx.x, g = blockIdx.y;
    int t = threadIdx.x;
    if (t >= 160) return;
    int c = t * 4;
    u16x4 o = {0, 0, 0, 0};
    if (r < NDRUG) {
        const float* src = AmatF + (long)g * ASTRIDE + (long)r * NDRUG;
        const float* dv = dinv + g * NDRUG;
        float dr = dv[r];
#pragma unroll
        for (int j = 0; j < 4; j++) {
            int cc = c + j;
            if (cc < NDRUG) o[j] = f2bf(src[cc] * dv[cc] * dr);
        }
    }
    *(u16x4*)(Amatb + (long)g * ABSTRIDE + (long)r * MPAD + c) = o;
}

__global__ void conv_dm1(const float* dm1, unsigned short* dm1b) {
    int r = blockIdx.x;
    int c = threadIdx.x * 4;
    u16x4 o = {0, 0, 0, 0};
    if (r < NDRUG) {
        float4 v = *(const float4*)(dm1 + (long)r * FDIM + c);
        o[0] = f2bf(v.x); o[1] = f2bf(v.y); o[2] = f2bf(v.z); o[3] = f2bf(v.w);
    }
    *(u16x4*)(dm1b + (long)r * FDIM + c) = o;
}

__global__ void conv_w6(const float* w0, const float* w1, const float* w2,
                        const float* w3, const float* w4, const float* w5,
                        unsigned short* WTb) {
    __shared__ float s[32][33];
    int z = blockIdx.z;
    const float* W = (z == 0) ? w0 : (z == 1) ? w1 : (z == 2) ? w2
                   : (z == 3) ? w3 : (z == 4) ? w4 : w5;
    unsigned short* WT = WTb + (long)z * WSTRIDE;
    int n0 = blockIdx.x * 32, k0 = blockIdx.y * 32;
    int tx = threadIdx.x & 31, ty = threadIdx.x >> 5;
#pragma unroll
    for (int q = 0; q < 4; q++)
        s[ty + 8 * q][tx] = W[(long)(k0 + ty + 8 * q) * FDIM + n0 + tx];
    __syncthreads();
#pragma unroll
    for (int q = 0; q < 4; q++)
        WT[(long)(n0 + ty + 8 * q) * FDIM + k0 + tx] = f2bf(s[tx][ty + 8 * q]);
}

template <int EPI>
__global__ __launch_bounds__(256) void gemm_wrap(
    const unsigned short* __restrict__ Abase, long strideA, int ldaK,
    const unsigned short* __restrict__ Bbase, long strideB, int ldbK,
    const float* __restrict__ bias0, const float* __restrict__ bias1,
    const float* __restrict__ bias2,
    unsigned short* __restrict__ Cbase, long strideC, int ldC, int K,
    float* __restrict__ poolacc, int layer)
{
    __shared__ unsigned short ldsA[2][4096];
    __shared__ unsigned short ldsB[2][4096];
    __shared__ float aux[64];
    int g = blockIdx.z;
    const float* bias = (g == 0) ? bias0 : (g == 1) ? bias1 : bias2;
    gemm_tile<EPI>(Abase + (long)g * strideA, ldaK, Bbase + (long)g * strideB, ldbK, bias,
                   Cbase + (long)g * strideC, ldC, K,
                   poolacc ? poolacc + 2 * g + layer : nullptr,
                   blockIdx.y * 64, blockIdx.x * 64, ldsA, ldsB, aux);
}

__global__ void mlp_kernel(const float* acc, const float* fc1w, const float* fc1b,
                           const float* fc2w, const float* fc2b, const float* convw,
                           float* wout) {
    __shared__ float hsh[30], plsh[6];
    int t = threadIdx.x;
    const float inv = 1.0f / (float)REAL;
    if (t < 6) plsh[t] = acc[t] * inv;
    __syncthreads();
    if (t < 30) {
        float s = fc1b[t];
#pragma unroll
        for (int c = 0; c < 6; c++) s += plsh[c] * fc1w[t * 6 + c];
        hsh[t] = fmaxf(s, 0.f);
    }
    __syncthreads();
    float hv = (t < 30) ? hsh[t] : 0.f;
    for (int j = 0; j < 6; j++) {
        float pr = (t < 30) ? hv * fc2w[j * 30 + t] : 0.f;
#pragma unroll
        for (int off = 32; off > 0; off >>= 1) pr += __shfl_down(pr, off);
        if (t == 0) wout[j] = convw[j] / (1.f + expf(-(fc2b[j] + pr)));
    }
}

__global__ void combine_kernel(const unsigned short* h1b, const unsigned short* h2b,
                               const float* wv, const float* convb, float* out) {
    int i = blockIdx.x * 256 + threadIdx.x;
    const int nv = REAL / 8;
    if (i >= nv) return;
    float cb = convb[0];
    float r8[8];
#pragma unroll
    for (int j = 0; j < 8; j++) r8[j] = cb;
#define ACCCH(c, ptr) do {                                          \
        float wc = wv[c];                                           \
        bf16x8 v = *(const bf16x8*)((ptr) + (long)i * 8);           \
        _Pragma("unroll")                                           \
        for (int j = 0; j < 8; j++) r8[j] += wc * bf2f((unsigned short)v[j]); \
} while (0)
    ACCCH(0, h1b);
    ACCCH(1, h2b);
    ACCCH(2, h1b + HSTRIDE);
    ACCCH(3, h2b + HSTRIDE);
    ACCCH(4, h1b + 2 * HSTRIDE);
    ACCCH(5, h2b + 2 * HSTRIDE);
#undef ACCCH
    *(float4*)(out + (long)i * 8)     = make_float4(r8[0], r8[1], r8[2], r8[3]);
    *(float4*)(out + (long)i * 8 + 4) = make_float4(r8[4], r8[5], r8[6], r8[7]);
}

extern "C" void kernel_launch(void* const* d_in, const int* in_sizes, int n_in,
                              void* d_out, int out_size, void* d_ws, size_t ws_size,
                              hipStream_t stream) {
    MegaParams p;
    p.dm1 = (const float*)d_in[0];
    p.et = (const int*)d_in[1];  p.wt = (const float*)d_in[2];
    p.es = (const int*)d_in[3];  p.ws = (const float*)d_in[4];
    p.eg = (const int*)d_in[5];  p.wg = (const float*)d_in[6];
    p.W[0] = (const float*)d_in[7];   p.b1[0] = (const float*)d_in[8];    // t1
    p.W[3] = (const float*)d_in[9];   p.b2[0] = (const float*)d_in[10];   // t2
    p.W[1] = (const float*)d_in[11];  p.b1[1] = (const float*)d_in[12];   // s1
    p.W[4] = (const float*)d_in[13];  p.b2[1] = (const float*)d_in[14];   // s2
    p.W[2] = (const float*)d_in[15];  p.b1[2] = (const float*)d_in[16];   // g1
    p.W[5] = (const float*)d_in[17];  p.b2[2] = (const float*)d_in[18];   // g2
    p.fc1w = (const float*)d_in[19]; p.fc1b = (const float*)d_in[20];
    p.fc2w = (const float*)d_in[21]; p.fc2b = (const float*)d_in[22];
    p.convw = (const float*)d_in[23]; p.convb = (const float*)d_in[24];
    p.out = (float*)d_out;

    char* base = (char*)d_ws;
    size_t o = 0;
    auto alloc = [&](size_t bytes) { void* ptr = base + o; o += (bytes + 255) & ~(size_t)255; return ptr; };
    p.AmatF = (float*)alloc((size_t)3 * ASTRIDE * 4);
    p.WTb   = (unsigned short*)alloc((size_t)6 * WSTRIDE * 2);
    p.dinv  = (float*)alloc(8192);
    p.scal  = (float*)alloc(256);
    p.dm1b  = (unsigned short*)alloc((size_t)MPAD * FDIM * 2);
    p.Amatb = (unsigned short*)alloc((size_t)3 * ABSTRIDE * 2);
    p.xwT   = (unsigned short*)alloc((size_t)3 * HSTRIDE * 2);
    p.h1b   = (unsigned short*)alloc((size_t)3 * HSTRIDE * 2);
    p.h2b   = (unsigned short*)alloc((size_t)3 * HSTRIDE * 2);
    if (ws_size < o) return;   // ~32.4 MB

    void* args[] = { (void*)&p };
    hipError_t err = hipLaunchCooperativeKernel((const void*)mega, dim3(NBLK), dim3(NTHR),
                                                args, 0, stream);
    if (err == hipSuccess) return;

    // ---------- fallback: proven 12-dispatch path ----------
    init_kernel<<<(3 * ASTRIDE / 4 + 256) / 256, 256, 0, stream>>>(p.AmatF, p.scal);
    scatter_kernel<<<(3 * (NEDGE + NDRUG) + 255) / 256, 256, 0, stream>>>(
        p.et, p.wt, p.es, p.ws, p.eg, p.wg, p.AmatF);
    rowdeg_kernel<<<dim3(NDRUG, 3), 64, 0, stream>>>(p.AmatF, p.dinv);
    conv_A<<<dim3(MPAD, 3), 256, 0, stream>>>(p.AmatF, p.dinv, p.Amatb);
    conv_w6<<<dim3(32, 32, 6), 256, 0, stream>>>(
        p.W[0], p.W[1], p.W[2], p.W[3], p.W[4], p.W[5], p.WTb);
    conv_dm1<<<MPAD, 256, 0, stream>>>(p.dm1, p.dm1b);

    dim3 gg(FDIM / 64, MPAD / 64, 3);
    gemm_wrap<0><<<gg, 256, 0, stream>>>(
        p.dm1b, 0L, FDIM, p.WTb, (long)WSTRIDE, FDIM,
        nullptr, nullptr, nullptr, p.xwT, (long)HSTRIDE, MPAD, FDIM, p.scal, 0);
    gemm_wrap<1><<<gg, 256, 0, stream>>>(
        p.Amatb, (long)ABSTRIDE, MPAD, p.xwT, (long)HSTRIDE, MPAD,
        p.b1[0], p.b1[1], p.b1[2], p.h1b, (long)HSTRIDE, FDIM, MPAD, p.scal, 0);
    gemm_wrap<0><<<gg, 256, 0, stream>>>(
        p.h1b, (long)HSTRIDE, FDIM, p.WTb + (size_t)3 * WSTRIDE, (long)WSTRIDE, FDIM,
        nullptr, nullptr, nullptr, p.xwT, (long)HSTRIDE, MPAD, FDIM, p.scal, 0);
    gemm_wrap<1><<<gg, 256, 0, stream>>>(
        p.Amatb, (long)ABSTRIDE, MPAD, p.xwT, (long)HSTRIDE, MPAD,
        p.b2[0], p.b2[1], p.b2[2], p.h2b, (long)HSTRIDE, FDIM, MPAD, p.scal, 1);

    mlp_kernel<<<1, 64, 0, stream>>>(p.scal, p.fc1w, p.fc1b, p.fc2w, p.fc2b, p.convw,
                                     p.scal + 8);
    combine_kernel<<<(REAL / 8 + 255) / 256, 256, 0, stream>>>(p.h1b, p.h2b, p.scal + 8,
                                                               p.convb, p.out);
}

// Round 11
// 276.588 us; speedup vs baseline: 1.8836x; 1.8836x over previous
//
#include <hip/hip_runtime.h>

#define NDRUG 591
#define FDIM 1024
#define NEDGE 120000
#define MPAD 640
#define ASTRIDE 349281          // 591*591 fp32 temp adjacency
#define ABSTRIDE (MPAD*MPAD)
#define HSTRIDE (MPAD*FDIM)
#define REAL (NDRUG*FDIM)
#define WSTRIDE (FDIM*FDIM)

typedef __attribute__((ext_vector_type(8))) short bf16x8;
typedef __attribute__((ext_vector_type(4))) float f32x4;
typedef __attribute__((ext_vector_type(4))) unsigned short u16x4;

static __device__ __forceinline__ unsigned short f2bf(float f) {
    unsigned u = __builtin_bit_cast(unsigned, f);
    u += 0x7fffu + ((u >> 16) & 1u);            // RNE
    return (unsigned short)(u >> 16);
}
static __device__ __forceinline__ float bf2f(unsigned short h) {
    return __builtin_bit_cast(float, ((unsigned)h) << 16);
}

// ---------------- prep kernels (R8-proven) ----------------
__global__ void init_kernel(float* AmatF, float* scal) {
    int i = blockIdx.x * blockDim.x + threadIdx.x;
    const int TOT = 3 * ASTRIDE;
    int b = i * 4;
    if (b + 3 < TOT) *(float4*)(AmatF + b) = make_float4(0.f, 0.f, 0.f, 0.f);
    else if (b < TOT) { for (int j = b; j < TOT; ++j) AmatF[j] = 0.f; }
    if (i < 16) scal[i] = 0.f;
}

__global__ void scatter_kernel(const int* e_t, const float* w_t,
                               const int* e_s, const float* w_s,
                               const int* e_g, const float* w_g, float* AmatF) {
    int i = blockIdx.x * blockDim.x + threadIdx.x;
    const int PER = NEDGE + NDRUG;
    if (i >= 3 * PER) return;
    int g = i / PER, r = i - g * PER;
    float* Ag = AmatF + (long)g * ASTRIDE;
    if (r < NEDGE) {
        const int*   E_ = (g == 0) ? e_t : (g == 1) ? e_s : e_g;
        const float* W_ = (g == 0) ? w_t : (g == 1) ? w_s : w_g;
        atomicAdd(Ag + (long)E_[NEDGE + r] * NDRUG + E_[r], W_[r]);
    } else {
        int n = r - NEDGE;
        atomicAdd(Ag + (long)n * NDRUG + n, 1.0f);
    }
}

__global__ void rowdeg_kernel(const float* AmatF, float* dinv) {
    int r = blockIdx.x, g = blockIdx.y;
    const float* row = AmatF + (long)g * ASTRIDE + (long)r * NDRUG;
    float s = 0.f;
    for (int c = threadIdx.x; c < NDRUG; c += 64) s += row[c];
#pragma unroll
    for (int off = 32; off > 0; off >>= 1) s += __shfl_down(s, off);
    if (threadIdx.x == 0) dinv[g * NDRUG + r] = (s > 0.f) ? rsqrtf(s) : 0.f;
}

__global__ void conv_A(const float* AmatF, const float* dinv, unsigned short* Amatb) {
    int r = blockIdx.x, g = blockIdx.y;
    int t = threadIdx.x;
    if (t >= 160) return;
    int c = t * 4;
    u16x4 o = {0, 0, 0, 0};
    if (r < NDRUG) {
        const float* src = AmatF + (long)g * ASTRIDE + (long)r * NDRUG;
        const float* dv = dinv + g * NDRUG;
        float dr = dv[r];
#pragma unroll
        for (int j = 0; j < 4; j++) {
            int cc = c + j;
            if (cc < NDRUG) o[j] = f2bf(src[cc] * dv[cc] * dr);
        }
    }
    *(u16x4*)(Amatb + (long)g * ABSTRIDE + (long)r * MPAD + c) = o;
}

__global__ void conv_dm1(const float* dm1, unsigned short* dm1b) {
    int r = blockIdx.x;
    int c = threadIdx.x * 4;
    u16x4 o = {0, 0, 0, 0};
    if (r < NDRUG) {
        float4 v = *(const float4*)(dm1 + (long)r * FDIM + c);
        o[0] = f2bf(v.x); o[1] = f2bf(v.y); o[2] = f2bf(v.z); o[3] = f2bf(v.w);
    }
    *(u16x4*)(dm1b + (long)r * FDIM + c) = o;
}

__global__ void conv_w6(const float* w0, const float* w1, const float* w2,
                        const float* w3, const float* w4, const float* w5,
                        unsigned short* WTb) {
    __shared__ float s[32][33];
    int z = blockIdx.z;
    const float* W = (z == 0) ? w0 : (z == 1) ? w1 : (z == 2) ? w2
                   : (z == 3) ? w3 : (z == 4) ? w4 : w5;
    unsigned short* WT = WTb + (long)z * WSTRIDE;
    int n0 = blockIdx.x * 32, k0 = blockIdx.y * 32;
    int tx = threadIdx.x & 31, ty = threadIdx.x >> 5;
#pragma unroll
    for (int q = 0; q < 4; q++)
        s[ty + 8 * q][tx] = W[(long)(k0 + ty + 8 * q) * FDIM + n0 + tx];
    __syncthreads();
#pragma unroll
    for (int q = 0; q < 4; q++)
        WT[(long)(n0 + ty + 8 * q) * FDIM + k0 + tx] = f2bf(s[tx][ty + 8 * q]);
}

// ---------------- register-streaming MFMA GEMM (no LDS, no barriers) ----------------
// One wave owns a 32x64 output tile. Fragments loaded directly from global (L2).
// 960 waves = 240 blocks x 4. EPI=0: C^T store; EPI=1: +bias relu + per-wave pool atomic.
template <int EPI>
__global__ __launch_bounds__(256) void gemm_rs(
    const unsigned short* __restrict__ Abase, long strideA, int ldaK,
    const unsigned short* __restrict__ Bbase, long strideB, int ldbK,
    const float* __restrict__ bias0, const float* __restrict__ bias1,
    const float* __restrict__ bias2,
    unsigned short* __restrict__ Cbase, long strideC, int ldC, int K,
    float* __restrict__ poolacc, int layer)
{
    const int wt = blockIdx.x * 4 + (threadIdx.x >> 6);   // 0..959
    const int g = wt / 320, rem = wt - g * 320;
    const int m0 = (rem >> 4) * 32;                       // 20 m-tiles of 32
    const int n0 = (rem & 15) * 64;                       // 16 n-tiles of 64
    const int lane = threadIdx.x & 63, l15 = lane & 15, lq = lane >> 4;

    const unsigned short* A = Abase + (long)g * strideA;
    const unsigned short* B = Bbase + (long)g * strideB;
    unsigned short* C = Cbase + (long)g * strideC;
    const float* bias = (g == 0) ? bias0 : (g == 1) ? bias1 : bias2;

    // per-lane fragment base pointers (16B per load, 16 rows x 64B coalesced/wave)
    const unsigned short* pa0 = A + (long)(m0 + l15) * ldaK + lq * 8;
    const unsigned short* pa1 = pa0 + (long)16 * ldaK;
    const unsigned short* pb0 = B + (long)(n0 + l15) * ldbK + lq * 8;
    const unsigned short* pb1 = pb0 + (long)16 * ldbK;
    const unsigned short* pb2 = pb0 + (long)32 * ldbK;
    const unsigned short* pb3 = pb0 + (long)48 * ldbK;

    f32x4 a00 = {0,0,0,0}, a01 = {0,0,0,0}, a02 = {0,0,0,0}, a03 = {0,0,0,0};
    f32x4 a10 = {0,0,0,0}, a11 = {0,0,0,0}, a12 = {0,0,0,0}, a13 = {0,0,0,0};

    bf16x8 a0c, a1c, b0c, b1c, b2c, b3c;
    bf16x8 a0n, a1n, b0n, b1n, b2n, b3n;

#define LOADF(sfx, kk) do {                         \
    a0##sfx = *(const bf16x8*)(pa0 + (kk));         \
    a1##sfx = *(const bf16x8*)(pa1 + (kk));         \
    b0##sfx = *(const bf16x8*)(pb0 + (kk));         \
    b1##sfx = *(const bf16x8*)(pb1 + (kk));         \
    b2##sfx = *(const bf16x8*)(pb2 + (kk));         \
    b3##sfx = *(const bf16x8*)(pb3 + (kk));         \
} while (0)
#define MFMA8(sfx) do {                                                         \
    a00 = __builtin_amdgcn_mfma_f32_16x16x32_bf16(a0##sfx, b0##sfx, a00, 0,0,0);\
    a01 = __builtin_amdgcn_mfma_f32_16x16x32_bf16(a0##sfx, b1##sfx, a01, 0,0,0);\
    a02 = __builtin_amdgcn_mfma_f32_16x16x32_bf16(a0##sfx, b2##sfx, a02, 0,0,0);\
    a03 = __builtin_amdgcn_mfma_f32_16x16x32_bf16(a0##sfx, b3##sfx, a03, 0,0,0);\
    a10 = __builtin_amdgcn_mfma_f32_16x16x32_bf16(a1##sfx, b0##sfx, a10, 0,0,0);\
    a11 = __builtin_amdgcn_mfma_f32_16x16x32_bf16(a1##sfx, b1##sfx, a11, 0,0,0);\
    a12 = __builtin_amdgcn_mfma_f32_16x16x32_bf16(a1##sfx, b2##sfx, a12, 0,0,0);\
    a13 = __builtin_amdgcn_mfma_f32_16x16x32_bf16(a1##sfx, b3##sfx, a13, 0,0,0);\
} while (0)

    LOADF(c, 0);
    for (int kk = 0; kk < K; kk += 64) {
        LOADF(n, kk + 32);
        MFMA8(c);
        if (kk + 64 < K) LOADF(c, kk + 64);
        MFMA8(n);
    }
#undef LOADF
#undef MFMA8

    if (EPI == 0) {
#define TSTORE(accv, i, j) do {                                     \
        int nn = n0 + (j) * 16 + l15;                               \
        int mm = m0 + (i) * 16 + lq * 4;                            \
        u16x4 pk;                                                   \
        pk[0] = f2bf(accv[0]); pk[1] = f2bf(accv[1]);               \
        pk[2] = f2bf(accv[2]); pk[3] = f2bf(accv[3]);               \
        *(u16x4*)&C[(long)nn * ldC + mm] = pk;                      \
} while (0)
        TSTORE(a00, 0, 0); TSTORE(a01, 0, 1); TSTORE(a02, 0, 2); TSTORE(a03, 0, 3);
        TSTORE(a10, 1, 0); TSTORE(a11, 1, 1); TSTORE(a12, 1, 2); TSTORE(a13, 1, 3);
#undef TSTORE
    } else {
        float spool = 0.f;
#define NSTORE(accv, i, j) do {                                     \
        int nn = n0 + (j) * 16 + l15;                               \
        int mm = m0 + (i) * 16 + lq * 4;                            \
        float bs = bias[nn];                                        \
        _Pragma("unroll")                                           \
        for (int r = 0; r < 4; r++) {                               \
            float v = fmaxf(accv[r] + bs, 0.f);                     \
            C[(long)(mm + r) * ldC + nn] = f2bf(v);                 \
            if (mm + r < NDRUG) spool += v;                         \
        }                                                           \
} while (0)
        NSTORE(a00, 0, 0); NSTORE(a01, 0, 1); NSTORE(a02, 0, 2); NSTORE(a03, 0, 3);
        NSTORE(a10, 1, 0); NSTORE(a11, 1, 1); NSTORE(a12, 1, 2); NSTORE(a13, 1, 3);
#undef NSTORE
#pragma unroll
        for (int off = 32; off > 0; off >>= 1) spool += __shfl_down(spool, off);
        if (lane == 0) atomicAdd(poolacc + 2 * g + layer, spool);
    }
}

// ---------------- SE MLP, 64-lane parallel ----------------
__global__ void mlp_kernel(const float* acc, const float* fc1w, const float* fc1b,
                           const float* fc2w, const float* fc2b, const float* convw,
                           float* wout) {
    __shared__ float hsh[30], plsh[6];
    int t = threadIdx.x;
    const float inv = 1.0f / (float)REAL;
    if (t < 6) plsh[t] = acc[t] * inv;
    __syncthreads();
    if (t < 30) {
        float s = fc1b[t];
#pragma unroll
        for (int c = 0; c < 6; c++) s += plsh[c] * fc1w[t * 6 + c];
        hsh[t] = fmaxf(s, 0.f);
    }
    __syncthreads();
    float hv = (t < 30) ? hsh[t] : 0.f;
    for (int j = 0; j < 6; j++) {
        float pr = (t < 30) ? hv * fc2w[j * 30 + t] : 0.f;
#pragma unroll
        for (int off = 32; off > 0; off >>= 1) pr += __shfl_down(pr, off);
        if (t == 0) wout[j] = convw[j] / (1.f + expf(-(fc2b[j] + pr)));
    }
}

__global__ void combine_kernel(const unsigned short* h1b, const unsigned short* h2b,
                               const float* wv, const float* convb, float* out) {
    int i = blockIdx.x * 256 + threadIdx.x;
    const int nv = REAL / 8;
    if (i >= nv) return;
    float cb = convb[0];
    float r8[8];
#pragma unroll
    for (int j = 0; j < 8; j++) r8[j] = cb;
#define ACCCH(c, ptr) do {                                          \
        float wc = wv[c];                                           \
        bf16x8 v = *(const bf16x8*)((ptr) + (long)i * 8);           \
        _Pragma("unroll")                                           \
        for (int j = 0; j < 8; j++) r8[j] += wc * bf2f((unsigned short)v[j]); \
} while (0)
    ACCCH(0, h1b);
    ACCCH(1, h2b);
    ACCCH(2, h1b + HSTRIDE);
    ACCCH(3, h2b + HSTRIDE);
    ACCCH(4, h1b + 2 * HSTRIDE);
    ACCCH(5, h2b + 2 * HSTRIDE);
#undef ACCCH
    *(float4*)(out + (long)i * 8)     = make_float4(r8[0], r8[1], r8[2], r8[3]);
    *(float4*)(out + (long)i * 8 + 4) = make_float4(r8[4], r8[5], r8[6], r8[7]);
}

extern "C" void kernel_launch(void* const* d_in, const int* in_sizes, int n_in,
                              void* d_out, int out_size, void* d_ws, size_t ws_size,
                              hipStream_t stream) {
    const float* dm1 = (const float*)d_in[0];
    const int* et = (const int*)d_in[1];  const float* wt = (const float*)d_in[2];
    const int* es = (const int*)d_in[3];  const float* ws = (const float*)d_in[4];
    const int* eg = (const int*)d_in[5];  const float* wg = (const float*)d_in[6];
    const float* W_t1 = (const float*)d_in[7];   const float* b_t1 = (const float*)d_in[8];
    const float* W_t2 = (const float*)d_in[9];   const float* b_t2 = (const float*)d_in[10];
    const float* W_s1 = (const float*)d_in[11];  const float* b_s1 = (const float*)d_in[12];
    const float* W_s2 = (const float*)d_in[13];  const float* b_s2 = (const float*)d_in[14];
    const float* W_g1 = (const float*)d_in[15];  const float* b_g1 = (const float*)d_in[16];
    const float* W_g2 = (const float*)d_in[17];  const float* b_g2 = (const float*)d_in[18];
    const float* fc1w = (const float*)d_in[19];  const float* fc1b = (const float*)d_in[20];
    const float* fc2w = (const float*)d_in[21];  const float* fc2b = (const float*)d_in[22];
    const float* convw = (const float*)d_in[23]; const float* convb = (const float*)d_in[24];
    float* out = (float*)d_out;

    char* base = (char*)d_ws;
    size_t o = 0;
    auto alloc = [&](size_t bytes) { void* p = base + o; o += (bytes + 255) & ~(size_t)255; return p; };
    float* AmatF = (float*)alloc((size_t)3 * ASTRIDE * 4);
    unsigned short* WTb   = (unsigned short*)alloc((size_t)6 * WSTRIDE * 2);
    float* dinv  = (float*)alloc(8192);
    float* scal  = (float*)alloc(256);
    unsigned short* dm1b  = (unsigned short*)alloc((size_t)MPAD * FDIM * 2);
    unsigned short* Amatb = (unsigned short*)alloc((size_t)3 * ABSTRIDE * 2);
    unsigned short* xwT   = (unsigned short*)alloc((size_t)3 * HSTRIDE * 2);
    unsigned short* h1b   = (unsigned short*)alloc((size_t)3 * HSTRIDE * 2);
    unsigned short* h2b   = (unsigned short*)alloc((size_t)3 * HSTRIDE * 2);
    if (ws_size < o) return;   // ~32.4 MB

    init_kernel<<<(3 * ASTRIDE / 4 + 256) / 256, 256, 0, stream>>>(AmatF, scal);
    scatter_kernel<<<(3 * (NEDGE + NDRUG) + 255) / 256, 256, 0, stream>>>(
        et, wt, es, ws, eg, wg, AmatF);
    rowdeg_kernel<<<dim3(NDRUG, 3), 64, 0, stream>>>(AmatF, dinv);
    conv_A<<<dim3(MPAD, 3), 256, 0, stream>>>(AmatF, dinv, Amatb);
    conv_w6<<<dim3(32, 32, 6), 256, 0, stream>>>(W_t1, W_s1, W_g1, W_t2, W_s2, W_g2, WTb);
    conv_dm1<<<MPAD, 256, 0, stream>>>(dm1, dm1b);

    // 960 waves = 240 blocks x 4; one 32x64 output tile per wave
    // stage 1: xwT = (dm1b @ W1)^T
    gemm_rs<0><<<240, 256, 0, stream>>>(
        dm1b, 0L, FDIM, WTb, (long)WSTRIDE, FDIM,
        nullptr, nullptr, nullptr, xwT, (long)HSTRIDE, MPAD, FDIM, scal, 0);
    // agg 1: h1 = relu(A @ xw + b1)  (+pool into scal[2g])
    gemm_rs<1><<<240, 256, 0, stream>>>(
        Amatb, (long)ABSTRIDE, MPAD, xwT, (long)HSTRIDE, MPAD,
        b_t1, b_s1, b_g1, h1b, (long)HSTRIDE, FDIM, MPAD, scal, 0);
    // stage 2: xwT = (h1 @ W2)^T
    gemm_rs<0><<<240, 256, 0, stream>>>(
        h1b, (long)HSTRIDE, FDIM, WTb + (size_t)3 * WSTRIDE, (long)WSTRIDE, FDIM,
        nullptr, nullptr, nullptr, xwT, (long)HSTRIDE, MPAD, FDIM, scal, 0);
    // agg 2: h2 = relu(A @ xw + b2)  (+pool into scal[2g+1])
    gemm_rs<1><<<240, 256, 0, stream>>>(
        Amatb, (long)ABSTRIDE, MPAD, xwT, (long)HSTRIDE, MPAD,
        b_t2, b_s2, b_g2, h2b, (long)HSTRIDE, FDIM, MPAD, scal, 1);

    mlp_kernel<<<1, 64, 0, stream>>>(scal, fc1w, fc1b, fc2w, fc2b, convw, scal + 8);
    combine_kernel<<<(REAL / 8 + 255) / 256, 256, 0, stream>>>(h1b, h2b, scal + 8, convb, out);
}